// Round 7
// baseline (108.171 us; speedup 1.0000x reference)
//
#include <hip/hip_runtime.h>
#include <hip/hip_fp16.h>

#define CC   256
#define QKC  32
#define NPIX 4096
#define NB   4
#define XSTR 264
#define VSTR 72
#define LOG2E 1.44269504088896340736f
#define TAU  8.0f

typedef __attribute__((ext_vector_type(8))) _Float16 f16x8;
typedef __attribute__((ext_vector_type(4))) float     f32x4;

static __device__ __forceinline__ unsigned h2bits(__half2 h) {
    union { __half2 h; unsigned u; } cv; cv.h = h; return cv.u;
}
#define E2(x) __builtin_amdgcn_exp2f(x)

// ---------------- W prep: Wh[320][256] f16 = [wv(256); wq(32)*log2e; wk(32)] ----------------
__global__ __launch_bounds__(256) void wh_prep(
    const float* __restrict__ wq, const float* __restrict__ wk,
    const float* __restrict__ wv, __half* __restrict__ Wh)
{
    const int idx4 = blockIdx.x * 256 + threadIdx.x;
    const int o  = idx4 >> 6;
    const int cw = (idx4 & 63) << 2;
    const float* src;
    float scale = 1.0f;
    if (o < 256)      src = wv + (size_t)o * 256 + cw;
    else if (o < 288) { src = wq + (size_t)(o - 256) * 256 + cw; scale = LOG2E; }
    else              src = wk + (size_t)(o - 288) * 256 + cw;
    const float4 v = *reinterpret_cast<const float4*>(src);
    __half h[4] = {__float2half(v.x * scale), __float2half(v.y * scale),
                   __float2half(v.z * scale), __float2half(v.w * scale)};
    *reinterpret_cast<uint2*>(Wh + (size_t)o * 256 + cw) =
        *reinterpret_cast<const uint2*>(h);
}

// ---------------- QKV projection via MFMA ----------------
__global__ __launch_bounds__(512) void qkv_mfma(
    const float* __restrict__ x, const __half* __restrict__ Wh,
    const float* __restrict__ bq, const float* __restrict__ bk,
    const float* __restrict__ bv,
    __half* __restrict__ Qh, __half* __restrict__ Kh, __half* __restrict__ VTh)
{
    __shared__ __align__(16) __half sm[CC * VSTR];
    __half* xT   = sm;
    __half* vres = sm;

    const int t  = threadIdx.x;
    const int b  = blockIdx.x >> 6;
    const int n0 = (blockIdx.x & 63) << 6;

    {
        const int nl4 = t & 15;
        const int c0  = t >> 4;
        const float* xp = x + ((size_t)b * CC) * NPIX + n0 + nl4 * 4;
        #pragma unroll
        for (int i = 0; i < 8; ++i) {
            const int c = c0 + 32 * i;
            const float4 v = *reinterpret_cast<const float4*>(xp + (size_t)c * NPIX);
            xT[(nl4 * 4 + 0) * XSTR + c] = __float2half(v.x);
            xT[(nl4 * 4 + 1) * XSTR + c] = __float2half(v.y);
            xT[(nl4 * 4 + 2) * XSTR + c] = __float2half(v.z);
            xT[(nl4 * 4 + 3) * XSTR + c] = __float2half(v.w);
        }
    }
    __syncthreads();

    const int w = t >> 6, l = t & 63, lr = l & 15, s = l >> 4;
    const int nto = (w < 4) ? 3 : 2;
    const int ob0 = 32 * w, ob1 = 32 * w + 16, ob2 = 256 + 16 * w;

    f16x8 wf[3][8];
    #pragma unroll
    for (int kk = 0; kk < 8; ++kk) {
        wf[0][kk] = *reinterpret_cast<const f16x8*>(
            Wh + (size_t)(ob0 + lr) * 256 + kk * 32 + s * 8);
        wf[1][kk] = *reinterpret_cast<const f16x8*>(
            Wh + (size_t)(ob1 + lr) * 256 + kk * 32 + s * 8);
    }
    if (w < 4)
        #pragma unroll
        for (int kk = 0; kk < 8; ++kk)
            wf[2][kk] = *reinterpret_cast<const f16x8*>(
                Wh + (size_t)(ob2 + lr) * 256 + kk * 32 + s * 8);

    f32x4 acc[3][4];
    #pragma unroll
    for (int j = 0; j < 3; ++j)
        #pragma unroll
        for (int nt = 0; nt < 4; ++nt) acc[j][nt] = (f32x4){0.f, 0.f, 0.f, 0.f};

    #pragma unroll
    for (int nt = 0; nt < 4; ++nt) {
        f16x8 xf[8];
        #pragma unroll
        for (int kk = 0; kk < 8; ++kk)
            xf[kk] = *reinterpret_cast<const f16x8*>(
                &xT[(nt * 16 + lr) * XSTR + kk * 32 + s * 8]);
        #pragma unroll
        for (int j = 0; j < 3; ++j)
            if (j < nto)
                #pragma unroll
                for (int kk = 0; kk < 8; ++kk)
                    acc[j][nt] = __builtin_amdgcn_mfma_f32_16x16x32_f16(
                        xf[kk], wf[j][kk], acc[j][nt], 0, 0, 0);
    }

    if (w < 4) {
        const bool is_q = (w < 2);
        const int oc = (w & 1) * 16 + lr;
        __half* dst = is_q ? Qh : Kh;
        const float bias = is_q ? bq[oc] * LOG2E : bk[oc];
        #pragma unroll
        for (int nt = 0; nt < 4; ++nt)
            #pragma unroll
            for (int r = 0; r < 4; ++r) {
                const size_t n = (size_t)b * NPIX + n0 + nt * 16 + s * 4 + r;
                dst[n * QKC + oc] = __float2half(acc[2][nt][r] + bias);
            }
    }

    __syncthreads();
    {
        #pragma unroll
        for (int j = 0; j < 2; ++j) {
            const int c = 32 * w + 16 * j + lr;
            const float bias = bv[c];
            #pragma unroll
            for (int nt = 0; nt < 4; ++nt) {
                __half h[4];
                #pragma unroll
                for (int r = 0; r < 4; ++r) h[r] = __float2half(acc[j][nt][r] + bias);
                *reinterpret_cast<uint2*>(&vres[c * VSTR + nt * 16 + s * 4]) =
                    *reinterpret_cast<const uint2*>(h);
            }
        }
    }
    __syncthreads();
    {
        const int c = t >> 1, half = t & 1;
        __half* dst = VTh + ((size_t)(b * CC + c)) * NPIX + n0 + half * 32;
        #pragma unroll
        for (int jj = 0; jj < 4; ++jj)
            *reinterpret_cast<uint4*>(dst + jj * 8) =
                *reinterpret_cast<const uint4*>(&vres[c * VSTR + half * 32 + jj * 8]);
    }
}

// ---------------- MFMA flash attention: 4 S + 4 PV waves, defer-rescale ----------------
__global__ __launch_bounds__(512) void attn_mfma(
    const __half* __restrict__ Qh, const __half* __restrict__ Kh,
    const __half* __restrict__ VTh, const float* __restrict__ x,
    const float* __restrict__ gamma, float* __restrict__ out)
{
    __shared__ unsigned char Praw[2][64 * 128];
    __shared__ float abuf[2][64];
    __shared__ __align__(16) int fbuf[2][4];
    __shared__ float lbuf[64];

    const int t  = threadIdx.x;
    const int w  = t >> 6;
    const int l  = t & 63;
    const int lr = l & 15;
    const int s  = l >> 4;

    const int blk = (blockIdx.x & 7) * 32 + (blockIdx.x >> 3);
    const int b  = blk >> 6;
    const int n0 = (blk & 63) << 6;

    // ---- S-wave state ----
    const int qw = w * 16 + lr;
    f16x8 qfrag;
    f16x8 kf[4];
    float m_run = -1e30f, l_run = 0.f;
    const __half* kbase = Kh + ((size_t)b * NPIX + lr) * QKC + s * 8;

    // ---- PV-wave state ----
    const int cbase = 64 * (w - 4);
    const __half* vbase = VTh + ((size_t)(b * CC + cbase + lr)) * NPIX + s * 8;
    f16x8 vA[4][2], vB[4][2];
    f32x4 O[4][4];
    #pragma unroll
    for (int ct = 0; ct < 4; ++ct)
        #pragma unroll
        for (int qt = 0; qt < 4; ++qt)
            O[ct][qt] = (f32x4){0.f, 0.f, 0.f, 0.f};

    auto do_softmax = [&](int bw) {
        f32x4 sacc[4];
        #pragma unroll
        for (int mt = 0; mt < 4; ++mt)
            sacc[mt] = __builtin_amdgcn_mfma_f32_16x16x32_f16(
                kf[mt], qfrag, (f32x4){0.f, 0.f, 0.f, 0.f}, 0, 0, 0);
        float v[16];
        #pragma unroll
        for (int mt = 0; mt < 4; ++mt)
            #pragma unroll
            for (int r = 0; r < 4; ++r) v[mt * 4 + r] = sacc[mt][r];
        // lane-local max (tree)
        float t8[8], t4[4], t2[2];
        #pragma unroll
        for (int i = 0; i < 8; ++i) t8[i] = fmaxf(v[i], v[i + 8]);
        #pragma unroll
        for (int i = 0; i < 4; ++i) t4[i] = fmaxf(t8[i], t8[i + 4]);
        t2[0] = fmaxf(t4[0], t4[2]); t2[1] = fmaxf(t4[1], t4[3]);
        const float m_l = fmaxf(t2[0], t2[1]);
        // lane-local exps + sum (tree)
        float p[16];
        #pragma unroll
        for (int i = 0; i < 16; ++i) p[i] = E2(v[i] - m_l);
        float s8[8], s4[4], s2[2];
        #pragma unroll
        for (int i = 0; i < 8; ++i) s8[i] = p[i] + p[i + 8];
        #pragma unroll
        for (int i = 0; i < 4; ++i) s4[i] = s8[i] + s8[i + 4];
        s2[0] = s4[0] + s4[2]; s2[1] = s4[1] + s4[3];
        const float e_l = s2[0] + s2[1];
        // cross-lane combine (butterfly over the 4 s-lanes of this q)
        float m_p = __shfl_xor(m_l, 16);
        float e_p = __shfl_xor(e_l, 16);
        const float m1 = fmaxf(m_l, m_p);
        const float e1 = e_l * E2(m_l - m1) + e_p * E2(m_p - m1);
        m_p = __shfl_xor(m1, 32);
        e_p = __shfl_xor(e1, 32);
        const float m_g = fmaxf(m1, m_p);
        const float e_g = e1 * E2(m1 - m_g) + e_p * E2(m_p - m_g);
        // defer-rescale decision (wave-uniform)
        const bool need = (m_g - m_run) > TAU;
        float f;
        if (__any(need)) {
            const float mnew = fmaxf(m_run, m_g);
            const float al   = E2(m_run - mnew);
            l_run = al * l_run + e_g * E2(m_g - mnew);
            f = E2(m_l - mnew);
            if (l < 16) abuf[bw][qw] = al;
            if (l == 0) fbuf[bw][w] = 1;
            m_run = mnew;
        } else {
            l_run += e_g * E2(m_g - m_run);
            f = E2(m_l - m_run);
            if (l < 16) abuf[bw][qw] = 1.0f;   // keep abuf valid for mixed-flag steps
            if (l == 0) fbuf[bw][w] = 0;
        }
        // pack P*f -> f16, swizzled b64 writes
        unsigned char* pb = &Praw[bw][0];
        #pragma unroll
        for (int mt = 0; mt < 4; ++mt) {
            const int g = ((s >> 1) + 2 * mt) ^ (qw & 7);
            uint2 u;
            u.x = h2bits(__floats2half2_rn(p[mt * 4 + 0] * f, p[mt * 4 + 1] * f));
            u.y = h2bits(__floats2half2_rn(p[mt * 4 + 2] * f, p[mt * 4 + 3] * f));
            *reinterpret_cast<uint2*>(pb + qw * 128 + g * 16 + (s & 1) * 8) = u;
        }
    };

    auto vload = [&](f16x8 (&dst)[4][2], int m0) {
        #pragma unroll
        for (int ct = 0; ct < 4; ++ct)
            #pragma unroll
            for (int ks = 0; ks < 2; ++ks)
                dst[ct][ks] = *reinterpret_cast<const f16x8*>(
                    vbase + (size_t)ct * 16 * NPIX + m0 + ks * 32);
    };

    auto pv_body = [&](int pbuf, f16x8 (&vf)[4][2]) {
        const int4 fl = *reinterpret_cast<const int4*>(&fbuf[pbuf][0]);
        if (fl.x | fl.y | fl.z | fl.w) {
            float av[4];
            #pragma unroll
            for (int qt = 0; qt < 4; ++qt) av[qt] = abuf[pbuf][qt * 16 + lr];
            #pragma unroll
            for (int ct = 0; ct < 4; ++ct)
                #pragma unroll
                for (int qt = 0; qt < 4; ++qt)
                    #pragma unroll
                    for (int r = 0; r < 4; ++r) O[ct][qt][r] *= av[qt];
        }
        const unsigned char* pr = &Praw[pbuf][0];
        __builtin_amdgcn_s_setprio(1);
        #pragma unroll
        for (int qt = 0; qt < 4; ++qt) {
            const int q2 = qt * 16 + lr;
            const int g0 = s ^ (q2 & 7);
            const int g1 = (s + 4) ^ (q2 & 7);
            const f16x8 pf0 = *reinterpret_cast<const f16x8*>(pr + q2 * 128 + g0 * 16);
            const f16x8 pf1 = *reinterpret_cast<const f16x8*>(pr + q2 * 128 + g1 * 16);
            #pragma unroll
            for (int ct = 0; ct < 4; ++ct) {
                O[ct][qt] = __builtin_amdgcn_mfma_f32_16x16x32_f16(
                    vf[ct][0], pf0, O[ct][qt], 0, 0, 0);
                O[ct][qt] = __builtin_amdgcn_mfma_f32_16x16x32_f16(
                    vf[ct][1], pf1, O[ct][qt], 0, 0, 0);
            }
        }
        __builtin_amdgcn_s_setprio(0);
    };

    // ---- prologue ----
    if (w < 4) {
        qfrag = *reinterpret_cast<const f16x8*>(
            Qh + ((size_t)b * NPIX + n0 + qw) * QKC + s * 8);
        #pragma unroll
        for (int mt = 0; mt < 4; ++mt)
            kf[mt] = *reinterpret_cast<const f16x8*>(kbase + (size_t)(mt * 16) * QKC);
        do_softmax(0);
        #pragma unroll
        for (int mt = 0; mt < 4; ++mt)
            kf[mt] = *reinterpret_cast<const f16x8*>(kbase + (size_t)(64 + mt * 16) * QKC);
    } else {
        vload(vA, 0);
    }
    __syncthreads();

    // ---- main loop: 32 iterations x 2 steps ----
    for (int it = 0; it < 32; ++it) {
        const int se = 2 * it;
        // EVEN body
        if (w < 4) {
            do_softmax(1);
            if (se < 62) {
                const size_t moff = (size_t)((se + 2) * 64) * QKC;
                #pragma unroll
                for (int mt = 0; mt < 4; ++mt)
                    kf[mt] = *reinterpret_cast<const f16x8*>(
                        kbase + moff + (size_t)(mt * 16) * QKC);
            }
        } else {
            vload(vB, (se + 1) * 64);
            pv_body(0, vA);
        }
        __syncthreads();
        // ODD body
        const int so = se + 1;
        if (w < 4) {
            if (so < 63) {
                do_softmax(0);
                if (so < 62) {
                    const size_t moff = (size_t)((so + 2) * 64) * QKC;
                    #pragma unroll
                    for (int mt = 0; mt < 4; ++mt)
                        kf[mt] = *reinterpret_cast<const f16x8*>(
                            kbase + moff + (size_t)(mt * 16) * QKC);
                }
            }
        } else {
            if (so < 63) vload(vA, (so + 1) * 64);
            pv_body(1, vB);
        }
        __syncthreads();
    }

    // ---- epilogue ----
    if (w < 4) { if (l < 16) lbuf[qw] = l_run; }
    __syncthreads();
    if (w >= 4) {
        const float g = gamma[0];
        float linv[4];
        #pragma unroll
        for (int qt = 0; qt < 4; ++qt) linv[qt] = g / lbuf[qt * 16 + lr];
        #pragma unroll
        for (int ct = 0; ct < 4; ++ct)
            #pragma unroll
            for (int qt = 0; qt < 4; ++qt)
                #pragma unroll
                for (int r = 0; r < 4; ++r) {
                    const int c = cbase + ct * 16 + s * 4 + r;
                    const size_t idx = ((size_t)(b * CC + c)) * NPIX + n0 + qt * 16 + lr;
                    out[idx] = O[ct][qt][r] * linv[qt] + x[idx];
                }
    }
}

extern "C" void kernel_launch(void* const* d_in, const int* in_sizes, int n_in,
                              void* d_out, int out_size, void* d_ws, size_t ws_size,
                              hipStream_t stream) {
    const float* x     = (const float*)d_in[0];
    const float* wq    = (const float*)d_in[1];
    const float* bq    = (const float*)d_in[2];
    const float* wk    = (const float*)d_in[3];
    const float* bk    = (const float*)d_in[4];
    const float* wv    = (const float*)d_in[5];
    const float* bv    = (const float*)d_in[6];
    const float* gamma = (const float*)d_in[7];
    float* out = (float*)d_out;

    __half* Wh  = (__half*)d_ws;
    __half* Qh  = Wh + (size_t)320 * 256;
    __half* Kh  = Qh + (size_t)NB * NPIX * QKC;
    __half* VTh = Kh + (size_t)NB * NPIX * QKC;

    hipLaunchKernelGGL(wh_prep, dim3(80), dim3(256), 0, stream, wq, wk, wv, Wh);
    hipLaunchKernelGGL(qkv_mfma, dim3(NB * 64), dim3(512), 0, stream,
                       x, Wh, bq, bk, bv, Qh, Kh, VTh);
    hipLaunchKernelGGL(attn_mfma, dim3(256), dim3(512), 0, stream,
                       Qh, Kh, VTh, x, gamma, out);
}